// Round 2
// baseline (173.661 us; speedup 1.0000x reference)
//
#include <hip/hip_runtime.h>
#include <math.h>

#define NB 128
#define SEQ 400
#define DIN 256
#define HID 128
#define NE 6
#define NQ 300
#define NC 6
#define NROW 300
#define M_TOTAL (NB*NROW)          // 38400
#define ROWS_BLK 64
#define NBLK (M_TOTAL/ROWS_BLK)    // 600
#define KCHUNK 64
#define NCHUNK (DIN/KCHUNK)        // 4
#define TAU 2e-3f
#define OUT_BBOX_SZ (NB*NQ*4)

// workspace layout (bytes)
#define WS_BITMAP_WORDS 1200       // 38400 bits
#define WS_W1BF_OFF 4864           // 4 chunks x 16384B of pre-swizzled bf16 W1

using short8 = __attribute__((ext_vector_type(8))) short;
using f32x4  = __attribute__((ext_vector_type(4))) float;

__device__ inline unsigned short bf16_rne(float f) {
    unsigned int u = __float_as_uint(f);
    unsigned int r = (u + 0x7FFFu + ((u >> 16) & 1u)) >> 16;
    return (unsigned short)r;
}

// ---------------- prep: W1 f32 -> bf16, pre-swizzled+pre-chunked; zero bitmap ----
__global__ __launch_bounds__(256)
void moe_prep(const float* __restrict__ W1, unsigned short* __restrict__ w1bf,
              unsigned int* __restrict__ bitmap)
{
    int g = blockIdx.x * 256 + threadIdx.x;
    if (blockIdx.x < 128) {
        int k = g >> 7;          // 0..255
        int n = g & 127;         // 0..127
        unsigned short h = bf16_rne(W1[k * 128 + n]);
        int c  = k >> 6;
        int k2 = (k & 63) << 1;  // kbyte within chunk row (0..126)
        // image identical to LDS B tile: [n][128B row] with XOR swizzle
        w1bf[(c * 16384 + n * 128 + (k2 ^ ((n & 7) << 4))) >> 1] = h;
    } else {
        int i = g - 128 * 256;
        if (i < WS_BITMAP_WORDS) bitmap[i] = 0u;
    }
}

// ---------------- main: MFMA GEMM1 (split-A bf16) + f32 GEMM2 + routing ---------
__global__ __launch_bounds__(256)
void moe_main(const float* __restrict__ features, const float* __restrict__ b1,
              const unsigned short* __restrict__ w1bf, const float* __restrict__ W2,
              const float* __restrict__ b2, const float* __restrict__ ebox,
              const float* __restrict__ ecls, unsigned int* __restrict__ bitmap,
              float* __restrict__ out)
{
    // LDS: A_hi [0,8192) bf16 64x64 sw; A_lo [8192,16384); B [16384,32768) bf16 128x64 sw
    // epilogue alias: h tile f32 [64][132] = 33792B
    __shared__ __align__(16) char s_raw[34048];
    __shared__ __align__(16) float s_w2[HID * NE];

    const int t    = (int)threadIdx.x;
    const int lane = t & 63;
    const int wv   = t >> 6;           // wave 0..3, owns cols wv*32..+31
    const int row0 = (int)blockIdx.x * ROWS_BLK;
    const int r15  = lane & 15;
    const int kq4  = lane >> 4;        // 0..3

    for (int i = t; i < HID * NE; i += 256) s_w2[i] = W2[i];

    // per-thread A staging descriptors (4 slots, coalesced: 16 lanes = one row)
    int  arow[4]; int akq[4]; long fbase[4];
    #pragma unroll
    for (int i = 0; i < 4; ++i) {
        int slot = i * 256 + t;
        int r  = slot >> 4;
        int kq = slot & 15;
        arow[i] = r; akq[i] = kq;
        int rowg = row0 + r;
        int bb = rowg / NROW;
        int ss = rowg - bb * NROW;
        fbase[i] = (long)(bb * SEQ + ss) * DIN;
    }

    f32x4 acc[4][2] = {};

    for (int c = 0; c < NCHUNK; ++c) {
        __syncthreads();
        // --- B staging: copy pre-swizzled chunk image linearly (regs roundtrip) ---
        short8 breg[4];
        const short8* bsrc = (const short8*)(w1bf) + (size_t)c * 1024;
        #pragma unroll
        for (int i = 0; i < 4; ++i) breg[i] = bsrc[i * 256 + t];
        // --- A staging: load f32, split hi/lo bf16, swizzled ds_write ---
        #pragma unroll
        for (int i = 0; i < 4; ++i) {
            float4 v = *(const float4*)(features + fbase[i] + c * KCHUNK + akq[i] * 4);
            unsigned short hx = bf16_rne(v.x), hy = bf16_rne(v.y),
                           hz = bf16_rne(v.z), hw = bf16_rne(v.w);
            float lxf = v.x - __uint_as_float((unsigned int)hx << 16);
            float lyf = v.y - __uint_as_float((unsigned int)hy << 16);
            float lzf = v.z - __uint_as_float((unsigned int)hz << 16);
            float lwf = v.w - __uint_as_float((unsigned int)hw << 16);
            short4 hi4 = make_short4((short)hx, (short)hy, (short)hz, (short)hw);
            short4 lo4 = make_short4((short)bf16_rne(lxf), (short)bf16_rne(lyf),
                                     (short)bf16_rne(lzf), (short)bf16_rne(lwf));
            int off = arow[i] * 128 + ((akq[i] * 8) ^ ((arow[i] & 7) << 4));
            *(short4*)(s_raw + off)        = hi4;
            *(short4*)(s_raw + 8192 + off) = lo4;
        }
        #pragma unroll
        for (int i = 0; i < 4; ++i)
            *((short8*)(s_raw + 16384) + i * 256 + t) = breg[i];
        __syncthreads();

        // --- compute: 2 k-steps of K=32 ---
        #pragma unroll
        for (int ks = 0; ks < 2; ++ks) {
            const int kb = ks * 64 + kq4 * 16;  // kbyte base of this lane's frag
            short8 bf[2];
            #pragma unroll
            for (int nf = 0; nf < 2; ++nf) {
                int n = wv * 32 + nf * 16 + r15;
                bf[nf] = *(const short8*)(s_raw + 16384 + n * 128 + (kb ^ ((n & 7) << 4)));
            }
            #pragma unroll
            for (int mf = 0; mf < 4; ++mf) {
                int row  = mf * 16 + r15;
                int aoff = row * 128 + (kb ^ ((row & 7) << 4));
                short8 ah = *(const short8*)(s_raw + aoff);
                short8 al = *(const short8*)(s_raw + 8192 + aoff);
                #pragma unroll
                for (int nf = 0; nf < 2; ++nf) {
                    acc[mf][nf] = __builtin_amdgcn_mfma_f32_16x16x32_bf16(ah, bf[nf], acc[mf][nf], 0, 0, 0);
                    acc[mf][nf] = __builtin_amdgcn_mfma_f32_16x16x32_bf16(al, bf[nf], acc[mf][nf], 0, 0, 0);
                }
            }
        }
    }

    // --- epilogue: bias+relu, acc -> h tile in LDS (aliases A/B, barrier-safe) ---
    __syncthreads();
    float* s_h = (float*)s_raw;
    #pragma unroll
    for (int nf = 0; nf < 2; ++nf) {
        int col = wv * 32 + nf * 16 + r15;
        float bias = b1[col];
        #pragma unroll
        for (int mf = 0; mf < 4; ++mf) {
            int row = mf * 16 + kq4 * 4;
            #pragma unroll
            for (int r = 0; r < 4; ++r)
                s_h[(row + r) * 132 + col] = fmaxf(acc[mf][nf][r] + bias, 0.f);
        }
    }
    __syncthreads();

    // --- GEMM2: 4 threads/row, 32 hid each, vectorized LDS reads ---
    const int lrow = t >> 2;   // 0..63
    const int part = t & 3;    // 0..3
    float l[6] = {0.f, 0.f, 0.f, 0.f, 0.f, 0.f};
    {
        const float* hp = s_h + lrow * 132 + part * 32;
        const float* wp = s_w2 + part * 32 * NE;
        #pragma unroll
        for (int g = 0; g < 8; ++g) {
            float4 h4 = *(const float4*)(hp + g * 4);
            float w[24];
            #pragma unroll
            for (int q = 0; q < 6; ++q)
                *(float4*)(w + q * 4) = *(const float4*)(wp + g * 24 + q * 4);
            #pragma unroll
            for (int e = 0; e < 6; ++e)
                l[e] += h4.x * w[e] + h4.y * w[6 + e] + h4.z * w[12 + e] + h4.w * w[18 + e];
        }
    }
    #pragma unroll
    for (int e = 0; e < 6; ++e) { l[e] += __shfl_xor(l[e], 1); l[e] += __shfl_xor(l[e], 2); }

    if (part == 0) {
        float lg[NE];
        #pragma unroll
        for (int e = 0; e < NE; ++e) lg[e] = l[e] + b2[e];
        float m = lg[0];
        #pragma unroll
        for (int e = 1; e < NE; ++e) m = fmaxf(m, lg[e]);
        float p[NE]; float psum = 0.f;
        #pragma unroll
        for (int e = 0; e < NE; ++e) { p[e] = expf(lg[e] - m); psum += p[e]; }
        #pragma unroll
        for (int e = 0; e < NE; ++e) p[e] = p[e] / psum;

        int i0 = 0; float v0 = p[0];
        #pragma unroll
        for (int e = 1; e < NE; ++e) if (p[e] > v0) { v0 = p[e]; i0 = e; }
        int i1 = -1; float v1 = -1e38f;
        #pragma unroll
        for (int e = 0; e < NE; ++e) if (e != i0 && p[e] > v1) { v1 = p[e]; i1 = e; }
        float v2 = -1e38f;
        #pragma unroll
        for (int e = 0; e < NE; ++e) if (e != i0 && e != i1 && p[e] > v2) v2 = p[e];

        int rowg = row0 + lrow;
        if (v1 - v2 < TAU)  // selection not provably safe -> flag for f32 recompute
            atomicOr(&bitmap[rowg >> 5], 1u << (rowg & 31));

        float e1 = expf(v1 - v0);
        float rw0 = 1.f / (1.f + e1);
        float rw1 = e1 / (1.f + e1);

        int bb = rowg / NROW;
        int ss = rowg - bb * NROW;
        size_t bo0 = ((size_t)(i0 * NB + bb) * NQ + ss) * 4;
        size_t bo1 = ((size_t)(i1 * NB + bb) * NQ + ss) * 4;
        float4 g0 = *(const float4*)(ebox + bo0);
        float4 g1 = *(const float4*)(ebox + bo1);
        float4 ob;
        ob.x = rw0 * g0.x + rw1 * g1.x;
        ob.y = rw0 * g0.y + rw1 * g1.y;
        ob.z = rw0 * g0.z + rw1 * g1.z;
        ob.w = rw0 * g0.w + rw1 * g1.w;
        *(float4*)(out + (size_t)rowg * 4) = ob;

        size_t co0 = ((size_t)(i0 * NB + bb) * NQ + ss) * NC;
        size_t co1 = ((size_t)(i1 * NB + bb) * NQ + ss) * NC;
        float* oc = out + OUT_BBOX_SZ + (size_t)rowg * NC;
        #pragma unroll
        for (int k = 0; k < NC; ++k)
            oc[k] = rw0 * ecls[co0 + k] + rw1 * ecls[co1 + k];
    }
}

// ---------------- fix: f32 recompute of flagged (near-tie) rows -----------------
__global__ __launch_bounds__(256)
void moe_fix(const float* __restrict__ features, const float* __restrict__ W1,
             const float* __restrict__ b1, const float* __restrict__ W2,
             const float* __restrict__ b2, const float* __restrict__ ebox,
             const float* __restrict__ ecls, const unsigned int* __restrict__ bitmap,
             float* __restrict__ out)
{
    const int wv   = (int)threadIdx.x >> 6;
    const int lane = (int)threadIdx.x & 63;
    const int r0   = (int)blockIdx.x * 64 + wv * 16;

    unsigned int word = bitmap[r0 >> 5];
    unsigned int mask = (word >> (r0 & 31)) & 0xFFFFu;

    while (mask) {
        int i = __ffs(mask) - 1;
        mask &= mask - 1;
        int row = r0 + i;
        int bb = row / NROW;
        int ss = row - bb * NROW;
        const float* f = features + (size_t)(bb * SEQ + ss) * DIN;

        // h[j] for j=lane, lane+64 in f32, sequential-d order (matches np)
        float a0 = 0.f, a1 = 0.f;
        for (int d = 0; d < DIN; d += 4) {
            float4 f4 = *(const float4*)(f + d);
            a0 += f4.x * W1[(d + 0) * HID + lane];
            a0 += f4.y * W1[(d + 1) * HID + lane];
            a0 += f4.z * W1[(d + 2) * HID + lane];
            a0 += f4.w * W1[(d + 3) * HID + lane];
            a1 += f4.x * W1[(d + 0) * HID + 64 + lane];
            a1 += f4.y * W1[(d + 1) * HID + 64 + lane];
            a1 += f4.z * W1[(d + 2) * HID + 64 + lane];
            a1 += f4.w * W1[(d + 3) * HID + 64 + lane];
        }
        float h0 = fmaxf(a0 + b1[lane], 0.f);
        float h1 = fmaxf(a1 + b1[64 + lane], 0.f);

        float lg[NE];
        #pragma unroll
        for (int e = 0; e < NE; ++e) {
            float v = h0 * W2[lane * NE + e] + h1 * W2[(64 + lane) * NE + e];
            #pragma unroll
            for (int off = 1; off < 64; off <<= 1) v += __shfl_xor(v, off);
            lg[e] = v + b2[e];
        }
        float m = lg[0];
        #pragma unroll
        for (int e = 1; e < NE; ++e) m = fmaxf(m, lg[e]);
        float p[NE]; float psum = 0.f;
        #pragma unroll
        for (int e = 0; e < NE; ++e) { p[e] = expf(lg[e] - m); psum += p[e]; }
        #pragma unroll
        for (int e = 0; e < NE; ++e) p[e] = p[e] / psum;

        int i0 = 0; float v0 = p[0];
        #pragma unroll
        for (int e = 1; e < NE; ++e) if (p[e] > v0) { v0 = p[e]; i0 = e; }
        int i1 = -1; float v1 = -1e38f;
        #pragma unroll
        for (int e = 0; e < NE; ++e) if (e != i0 && p[e] > v1) { v1 = p[e]; i1 = e; }

        if (lane == 0) {
            float e1 = expf(v1 - v0);
            float rw0 = 1.f / (1.f + e1);
            float rw1 = e1 / (1.f + e1);
            size_t bo0 = ((size_t)(i0 * NB + bb) * NQ + ss) * 4;
            size_t bo1 = ((size_t)(i1 * NB + bb) * NQ + ss) * 4;
            float4 g0 = *(const float4*)(ebox + bo0);
            float4 g1 = *(const float4*)(ebox + bo1);
            float4 ob;
            ob.x = rw0 * g0.x + rw1 * g1.x;
            ob.y = rw0 * g0.y + rw1 * g1.y;
            ob.z = rw0 * g0.z + rw1 * g1.z;
            ob.w = rw0 * g0.w + rw1 * g1.w;
            *(float4*)(out + (size_t)row * 4) = ob;
            size_t co0 = ((size_t)(i0 * NB + bb) * NQ + ss) * NC;
            size_t co1 = ((size_t)(i1 * NB + bb) * NQ + ss) * NC;
            float* oc = out + OUT_BBOX_SZ + (size_t)row * NC;
            #pragma unroll
            for (int k = 0; k < NC; ++k)
                oc[k] = rw0 * ecls[co0 + k] + rw1 * ecls[co1 + k];
        }
    }
}

extern "C" void kernel_launch(void* const* d_in, const int* in_sizes, int n_in,
                              void* d_out, int out_size, void* d_ws, size_t ws_size,
                              hipStream_t stream)
{
    const float* features = (const float*)d_in[0];
    const float* W1   = (const float*)d_in[1];
    const float* b1   = (const float*)d_in[2];
    const float* W2   = (const float*)d_in[3];
    const float* b2   = (const float*)d_in[4];
    const float* ebox = (const float*)d_in[5];
    const float* ecls = (const float*)d_in[6];
    float* out = (float*)d_out;

    unsigned int*   bitmap = (unsigned int*)d_ws;
    unsigned short* w1bf   = (unsigned short*)((char*)d_ws + WS_W1BF_OFF);

    hipLaunchKernelGGL(moe_prep, dim3(134), dim3(256), 0, stream, W1, w1bf, bitmap);
    hipLaunchKernelGGL(moe_main, dim3(NBLK), dim3(256), 0, stream,
                       features, b1, w1bf, W2, b2, ebox, ecls, bitmap, out);
    hipLaunchKernelGGL(moe_fix, dim3(NBLK), dim3(256), 0, stream,
                       features, W1, b1, W2, b2, ebox, ecls, bitmap, out);
}

// Round 3
// 52.267 us; speedup vs baseline: 3.3226x; 3.3226x over previous
//
#include <hip/hip_runtime.h>
#include <math.h>

#define NB 128
#define SEQ 400
#define DIN 256
#define HID 128
#define NE 6
#define NQ 300
#define NC 6
#define NROW 300
#define M_TOTAL (NB*NROW)          // 38400
#define ROWS_BLK 64
#define NBLK (M_TOTAL/ROWS_BLK)    // 600
#define KCHUNK 64
#define NCHUNK (DIN/KCHUNK)        // 4
#define TAU 2e-4f
#define OUT_BBOX_SZ (NB*NQ*4)

// workspace layout (bytes)
#define WS_BITMAP_WORDS 1200       // 38400 bits
#define WS_W1BF_OFF 4864           // 4 chunks x 16384B of pre-swizzled bf16 W1

using short8 = __attribute__((ext_vector_type(8))) short;
using f32x4  = __attribute__((ext_vector_type(4))) float;

__device__ inline unsigned short bf16_rne(float f) {
    unsigned int u = __float_as_uint(f);
    unsigned int r = (u + 0x7FFFu + ((u >> 16) & 1u)) >> 16;
    return (unsigned short)r;
}

// ---------------- prep: W1 f32 -> bf16, pre-swizzled+pre-chunked; zero bitmap ----
__global__ __launch_bounds__(256)
void moe_prep(const float* __restrict__ W1, unsigned short* __restrict__ w1bf,
              unsigned int* __restrict__ bitmap)
{
    int g = blockIdx.x * 256 + threadIdx.x;
    if (blockIdx.x < 128) {
        int k = g >> 7;          // 0..255
        int n = g & 127;         // 0..127
        unsigned short h = bf16_rne(W1[k * 128 + n]);
        int c  = k >> 6;
        int k2 = (k & 63) << 1;  // kbyte within chunk row (0..126)
        // image identical to LDS B tile: [n][128B row] with XOR swizzle
        w1bf[(c * 16384 + n * 128 + (k2 ^ ((n & 7) << 4))) >> 1] = h;
    } else {
        int i = g - 128 * 256;
        if (i < WS_BITMAP_WORDS) bitmap[i] = 0u;
    }
}

// ---------------- main: MFMA GEMM1 (split-A bf16) + f32 GEMM2 + routing ---------
__global__ __launch_bounds__(256)
void moe_main(const float* __restrict__ features, const float* __restrict__ b1,
              const unsigned short* __restrict__ w1bf, const float* __restrict__ W2,
              const float* __restrict__ b2, const float* __restrict__ ebox,
              const float* __restrict__ ecls, unsigned int* __restrict__ bitmap,
              float* __restrict__ out)
{
    // LDS: A_hi [0,8192) bf16 64x64 sw; A_lo [8192,16384); B [16384,32768) bf16 128x64 sw
    // epilogue alias: h tile f32 [64][132] = 33792B
    __shared__ __align__(16) char s_raw[34048];
    __shared__ __align__(16) float s_w2[HID * NE];

    const int t    = (int)threadIdx.x;
    const int lane = t & 63;
    const int wv   = t >> 6;           // wave 0..3, owns cols wv*32..+31
    const int row0 = (int)blockIdx.x * ROWS_BLK;
    const int r15  = lane & 15;
    const int kq4  = lane >> 4;        // 0..3

    for (int i = t; i < HID * NE; i += 256) s_w2[i] = W2[i];

    // per-thread A staging descriptors (4 slots, coalesced: 16 lanes = one row)
    int  arow[4]; int akq[4]; long fbase[4];
    #pragma unroll
    for (int i = 0; i < 4; ++i) {
        int slot = i * 256 + t;
        int r  = slot >> 4;
        int kq = slot & 15;
        arow[i] = r; akq[i] = kq;
        int rowg = row0 + r;
        int bb = rowg / NROW;
        int ss = rowg - bb * NROW;
        fbase[i] = (long)(bb * SEQ + ss) * DIN;
    }

    f32x4 acc[4][2] = {};

    for (int c = 0; c < NCHUNK; ++c) {
        __syncthreads();
        // --- B staging: copy pre-swizzled chunk image linearly (regs roundtrip) ---
        short8 breg[4];
        const short8* bsrc = (const short8*)(w1bf) + (size_t)c * 1024;
        #pragma unroll
        for (int i = 0; i < 4; ++i) breg[i] = bsrc[i * 256 + t];
        // --- A staging: load f32, split hi/lo bf16, swizzled ds_write ---
        #pragma unroll
        for (int i = 0; i < 4; ++i) {
            float4 v = *(const float4*)(features + fbase[i] + c * KCHUNK + akq[i] * 4);
            unsigned short hx = bf16_rne(v.x), hy = bf16_rne(v.y),
                           hz = bf16_rne(v.z), hw = bf16_rne(v.w);
            float lxf = v.x - __uint_as_float((unsigned int)hx << 16);
            float lyf = v.y - __uint_as_float((unsigned int)hy << 16);
            float lzf = v.z - __uint_as_float((unsigned int)hz << 16);
            float lwf = v.w - __uint_as_float((unsigned int)hw << 16);
            short4 hi4 = make_short4((short)hx, (short)hy, (short)hz, (short)hw);
            short4 lo4 = make_short4((short)bf16_rne(lxf), (short)bf16_rne(lyf),
                                     (short)bf16_rne(lzf), (short)bf16_rne(lwf));
            int off = arow[i] * 128 + ((akq[i] * 8) ^ ((arow[i] & 7) << 4));
            *(short4*)(s_raw + off)        = hi4;
            *(short4*)(s_raw + 8192 + off) = lo4;
        }
        #pragma unroll
        for (int i = 0; i < 4; ++i)
            *((short8*)(s_raw + 16384) + i * 256 + t) = breg[i];
        __syncthreads();

        // --- compute: 2 k-steps of K=32 ---
        #pragma unroll
        for (int ks = 0; ks < 2; ++ks) {
            const int kb = ks * 64 + kq4 * 16;  // kbyte base of this lane's frag
            short8 bf[2];
            #pragma unroll
            for (int nf = 0; nf < 2; ++nf) {
                int n = wv * 32 + nf * 16 + r15;
                bf[nf] = *(const short8*)(s_raw + 16384 + n * 128 + (kb ^ ((n & 7) << 4)));
            }
            #pragma unroll
            for (int mf = 0; mf < 4; ++mf) {
                int row  = mf * 16 + r15;
                int aoff = row * 128 + (kb ^ ((row & 7) << 4));
                short8 ah = *(const short8*)(s_raw + aoff);
                short8 al = *(const short8*)(s_raw + 8192 + aoff);
                #pragma unroll
                for (int nf = 0; nf < 2; ++nf) {
                    acc[mf][nf] = __builtin_amdgcn_mfma_f32_16x16x32_bf16(ah, bf[nf], acc[mf][nf], 0, 0, 0);
                    acc[mf][nf] = __builtin_amdgcn_mfma_f32_16x16x32_bf16(al, bf[nf], acc[mf][nf], 0, 0, 0);
                }
            }
        }
    }

    // --- epilogue: bias+relu, acc -> h tile in LDS (aliases A/B, barrier-safe) ---
    __syncthreads();
    float* s_h = (float*)s_raw;
    #pragma unroll
    for (int nf = 0; nf < 2; ++nf) {
        int col = wv * 32 + nf * 16 + r15;
        float bias = b1[col];
        #pragma unroll
        for (int mf = 0; mf < 4; ++mf) {
            int row = mf * 16 + kq4 * 4;
            #pragma unroll
            for (int r = 0; r < 4; ++r)
                s_h[(row + r) * 132 + col] = fmaxf(acc[mf][nf][r] + bias, 0.f);
        }
    }
    __syncthreads();

    // --- GEMM2: 4 threads/row, 32 hid each, vectorized LDS reads ---
    const int lrow = t >> 2;   // 0..63
    const int part = t & 3;    // 0..3
    float l[6] = {0.f, 0.f, 0.f, 0.f, 0.f, 0.f};
    {
        const float* hp = s_h + lrow * 132 + part * 32;
        const float* wp = s_w2 + part * 32 * NE;
        #pragma unroll
        for (int g = 0; g < 8; ++g) {
            float4 h4 = *(const float4*)(hp + g * 4);
            float w[24];
            #pragma unroll
            for (int q = 0; q < 6; ++q)
                *(float4*)(w + q * 4) = *(const float4*)(wp + g * 24 + q * 4);
            #pragma unroll
            for (int e = 0; e < 6; ++e)
                l[e] += h4.x * w[e] + h4.y * w[6 + e] + h4.z * w[12 + e] + h4.w * w[18 + e];
        }
    }
    #pragma unroll
    for (int e = 0; e < 6; ++e) { l[e] += __shfl_xor(l[e], 1); l[e] += __shfl_xor(l[e], 2); }

    if (part == 0) {
        float lg[NE];
        #pragma unroll
        for (int e = 0; e < NE; ++e) lg[e] = l[e] + b2[e];
        float m = lg[0];
        #pragma unroll
        for (int e = 1; e < NE; ++e) m = fmaxf(m, lg[e]);
        float p[NE]; float psum = 0.f;
        #pragma unroll
        for (int e = 0; e < NE; ++e) { p[e] = expf(lg[e] - m); psum += p[e]; }
        #pragma unroll
        for (int e = 0; e < NE; ++e) p[e] = p[e] / psum;

        int i0 = 0; float v0 = p[0];
        #pragma unroll
        for (int e = 1; e < NE; ++e) if (p[e] > v0) { v0 = p[e]; i0 = e; }
        int i1 = -1; float v1 = -1e38f;
        #pragma unroll
        for (int e = 0; e < NE; ++e) if (e != i0 && p[e] > v1) { v1 = p[e]; i1 = e; }
        float v2 = -1e38f;
        #pragma unroll
        for (int e = 0; e < NE; ++e) if (e != i0 && e != i1 && p[e] > v2) v2 = p[e];

        int rowg = row0 + lrow;
        if (v1 - v2 < TAU)  // selection not provably safe -> flag for f32 recompute
            atomicOr(&bitmap[rowg >> 5], 1u << (rowg & 31));

        float e1 = expf(v1 - v0);
        float rw0 = 1.f / (1.f + e1);
        float rw1 = e1 / (1.f + e1);

        int bb = rowg / NROW;
        int ss = rowg - bb * NROW;
        size_t bo0 = ((size_t)(i0 * NB + bb) * NQ + ss) * 4;
        size_t bo1 = ((size_t)(i1 * NB + bb) * NQ + ss) * 4;
        float4 g0 = *(const float4*)(ebox + bo0);
        float4 g1 = *(const float4*)(ebox + bo1);
        float4 ob;
        ob.x = rw0 * g0.x + rw1 * g1.x;
        ob.y = rw0 * g0.y + rw1 * g1.y;
        ob.z = rw0 * g0.z + rw1 * g1.z;
        ob.w = rw0 * g0.w + rw1 * g1.w;
        *(float4*)(out + (size_t)rowg * 4) = ob;

        size_t co0 = ((size_t)(i0 * NB + bb) * NQ + ss) * NC;
        size_t co1 = ((size_t)(i1 * NB + bb) * NQ + ss) * NC;
        float* oc = out + OUT_BBOX_SZ + (size_t)rowg * NC;
        #pragma unroll
        for (int k = 0; k < NC; ++k)
            oc[k] = rw0 * ecls[co0 + k] + rw1 * ecls[co1 + k];
    }
}

// ---------------- fix: f32 recompute of flagged (near-tie) rows -----------------
// Arithmetic per row is IDENTICAL to the validated round-2 fix (same FMA chain
// order). Changes are scheduling-only: block-wide 64-bit mask with round-robin
// row->wave assignment (load balance) and #pragma unroll 8 (load pipelining).
__global__ __launch_bounds__(256)
void moe_fix(const float* __restrict__ features, const float* __restrict__ W1,
             const float* __restrict__ b1, const float* __restrict__ W2,
             const float* __restrict__ b2, const float* __restrict__ ebox,
             const float* __restrict__ ecls, const unsigned int* __restrict__ bitmap,
             float* __restrict__ out)
{
    const int wv   = (int)threadIdx.x >> 6;
    const int lane = (int)threadIdx.x & 63;
    const int rb   = (int)blockIdx.x * 64;   // block's 64-row stripe

    unsigned long long m =
        ((unsigned long long)bitmap[(rb >> 5) + 1] << 32) | (unsigned long long)bitmap[rb >> 5];

    int k = 0;
    while (m) {
        int i = __builtin_ctzll(m);
        m &= m - 1;
        if (((k++) & 3) != wv) continue;
        int row = rb + i;
        int bb = row / NROW;
        int ss = row - bb * NROW;
        const float* f = features + (size_t)(bb * SEQ + ss) * DIN;

        // h[j] for j=lane, lane+64 in f32, sequential-d order (matches np)
        float a0 = 0.f, a1 = 0.f;
        #pragma unroll 8
        for (int d = 0; d < DIN; d += 4) {
            float4 f4 = *(const float4*)(f + d);
            a0 += f4.x * W1[(d + 0) * HID + lane];
            a0 += f4.y * W1[(d + 1) * HID + lane];
            a0 += f4.z * W1[(d + 2) * HID + lane];
            a0 += f4.w * W1[(d + 3) * HID + lane];
            a1 += f4.x * W1[(d + 0) * HID + 64 + lane];
            a1 += f4.y * W1[(d + 1) * HID + 64 + lane];
            a1 += f4.z * W1[(d + 2) * HID + 64 + lane];
            a1 += f4.w * W1[(d + 3) * HID + 64 + lane];
        }
        float h0 = fmaxf(a0 + b1[lane], 0.f);
        float h1 = fmaxf(a1 + b1[64 + lane], 0.f);

        float lg[NE];
        #pragma unroll
        for (int e = 0; e < NE; ++e) {
            float v = h0 * W2[lane * NE + e] + h1 * W2[(64 + lane) * NE + e];
            #pragma unroll
            for (int off = 1; off < 64; off <<= 1) v += __shfl_xor(v, off);
            lg[e] = v + b2[e];
        }
        float mx = lg[0];
        #pragma unroll
        for (int e = 1; e < NE; ++e) mx = fmaxf(mx, lg[e]);
        float p[NE]; float psum = 0.f;
        #pragma unroll
        for (int e = 0; e < NE; ++e) { p[e] = expf(lg[e] - mx); psum += p[e]; }
        #pragma unroll
        for (int e = 0; e < NE; ++e) p[e] = p[e] / psum;

        int i0 = 0; float v0 = p[0];
        #pragma unroll
        for (int e = 1; e < NE; ++e) if (p[e] > v0) { v0 = p[e]; i0 = e; }
        int i1 = -1; float v1 = -1e38f;
        #pragma unroll
        for (int e = 0; e < NE; ++e) if (e != i0 && p[e] > v1) { v1 = p[e]; i1 = e; }

        if (lane == 0) {
            float e1 = expf(v1 - v0);
            float rw0 = 1.f / (1.f + e1);
            float rw1 = e1 / (1.f + e1);
            size_t bo0 = ((size_t)(i0 * NB + bb) * NQ + ss) * 4;
            size_t bo1 = ((size_t)(i1 * NB + bb) * NQ + ss) * 4;
            float4 g0 = *(const float4*)(ebox + bo0);
            float4 g1 = *(const float4*)(ebox + bo1);
            float4 ob;
            ob.x = rw0 * g0.x + rw1 * g1.x;
            ob.y = rw0 * g0.y + rw1 * g1.y;
            ob.z = rw0 * g0.z + rw1 * g1.z;
            ob.w = rw0 * g0.w + rw1 * g1.w;
            *(float4*)(out + (size_t)row * 4) = ob;
            size_t co0 = ((size_t)(i0 * NB + bb) * NQ + ss) * NC;
            size_t co1 = ((size_t)(i1 * NB + bb) * NQ + ss) * NC;
            float* oc = out + OUT_BBOX_SZ + (size_t)row * NC;
            #pragma unroll
            for (int kk = 0; kk < NC; ++kk)
                oc[kk] = rw0 * ecls[co0 + kk] + rw1 * ecls[co1 + kk];
        }
    }
}

extern "C" void kernel_launch(void* const* d_in, const int* in_sizes, int n_in,
                              void* d_out, int out_size, void* d_ws, size_t ws_size,
                              hipStream_t stream)
{
    const float* features = (const float*)d_in[0];
    const float* W1   = (const float*)d_in[1];
    const float* b1   = (const float*)d_in[2];
    const float* W2   = (const float*)d_in[3];
    const float* b2   = (const float*)d_in[4];
    const float* ebox = (const float*)d_in[5];
    const float* ecls = (const float*)d_in[6];
    float* out = (float*)d_out;

    unsigned int*   bitmap = (unsigned int*)d_ws;
    unsigned short* w1bf   = (unsigned short*)((char*)d_ws + WS_W1BF_OFF);

    hipLaunchKernelGGL(moe_prep, dim3(134), dim3(256), 0, stream, W1, w1bf, bitmap);
    hipLaunchKernelGGL(moe_main, dim3(NBLK), dim3(256), 0, stream,
                       features, b1, w1bf, W2, b2, ebox, ecls, bitmap, out);
    hipLaunchKernelGGL(moe_fix, dim3(NBLK), dim3(256), 0, stream,
                       features, W1, b1, W2, b2, ebox, ecls, bitmap, out);
}

// Round 4
// 39.234 us; speedup vs baseline: 4.4263x; 1.3322x over previous
//
#include <hip/hip_runtime.h>
#include <math.h>

#define NB 128
#define SEQ 400
#define DIN 256
#define HID 128
#define NE 6
#define NQ 300
#define NC 6
#define NROW 300
#define M_TOTAL (NB*NROW)          // 38400
#define ROWS_BLK 64
#define NBLK (M_TOTAL/ROWS_BLK)    // 600
#define KCHUNK 64
#define NCHUNK (DIN/KCHUNK)        // 4
#define TAU 5e-5f
#define OUT_BBOX_SZ (NB*NQ*4)
#define FIX_GRID 1024

// workspace layout (bytes):
//   [0,4)            : worklist count (uint)
//   [1024, 1024+4*M) : worklist row ids
//   [155648, +131072): pre-swizzled bf16 W1, 4 chunks x (16KB hi | 16KB lo)
#define WS_ROWS_OFF  1024
#define WS_W1BF_OFF  155648

using short8 = __attribute__((ext_vector_type(8))) short;
using f32x4  = __attribute__((ext_vector_type(4))) float;

__device__ inline unsigned short bf16_rne(float f) {
    unsigned int u = __float_as_uint(f);
    unsigned int r = (u + 0x7FFFu + ((u >> 16) & 1u)) >> 16;
    return (unsigned short)r;
}

// ---- prep: W1 f32 -> bf16 hi+lo planes, pre-swizzled+pre-chunked; zero count ----
__global__ __launch_bounds__(256)
void moe_prep(const float* __restrict__ W1, unsigned short* __restrict__ w1bf,
              unsigned int* __restrict__ count)
{
    if (blockIdx.x == 128) { if (threadIdx.x == 0) count[0] = 0u; return; }
    int g = blockIdx.x * 256 + threadIdx.x;
    int k = g >> 7;          // 0..255
    int n = g & 127;         // 0..127
    float v = W1[k * 128 + n];
    unsigned short hi = bf16_rne(v);
    float lof = v - __uint_as_float((unsigned int)hi << 16);
    unsigned short lo = bf16_rne(lof);
    int c  = k >> 6;
    int k2 = (k & 63) << 1;  // kbyte within chunk row
    int base = c * 32768 + n * 128 + (k2 ^ ((n & 7) << 4));
    w1bf[base >> 1]             = hi;
    w1bf[(base + 16384) >> 1]   = lo;
}

// ---- main: split-split bf16 MFMA GEMM1 + f32 GEMM2 + routing + worklist flag ----
__global__ __launch_bounds__(256)
void moe_main(const float* __restrict__ features, const float* __restrict__ b1,
              const unsigned short* __restrict__ w1bf, const float* __restrict__ W2,
              const float* __restrict__ b2, const float* __restrict__ ebox,
              const float* __restrict__ ecls, unsigned int* __restrict__ count,
              int* __restrict__ rows, float* __restrict__ out)
{
    // LDS: A_hi [0,8K); A_lo [8K,16K); B_hi [16K,32K); B_lo [32K,48K)
    // epilogue alias: h tile f32 [64][132] = 33792B
    __shared__ __align__(16) char s_raw[49152];
    __shared__ __align__(16) float s_w2[HID * NE];

    const int t    = (int)threadIdx.x;
    const int lane = t & 63;
    const int wv   = t >> 6;           // wave 0..3, owns cols wv*32..+31
    const int row0 = (int)blockIdx.x * ROWS_BLK;
    const int r15  = lane & 15;
    const int kq4  = lane >> 4;        // 0..3

    for (int i = t; i < HID * NE; i += 256) s_w2[i] = W2[i];

    // per-thread A staging descriptors (4 slots, 16 lanes = one row)
    int  arow[4]; int akq[4]; long fbase[4];
    #pragma unroll
    for (int i = 0; i < 4; ++i) {
        int slot = i * 256 + t;
        int r  = slot >> 4;
        int kq = slot & 15;
        arow[i] = r; akq[i] = kq;
        int rowg = row0 + r;
        int bb = rowg / NROW;
        int ss = rowg - bb * NROW;
        fbase[i] = (long)(bb * SEQ + ss) * DIN;
    }

    f32x4 acc[4][2] = {};

    for (int c = 0; c < NCHUNK; ++c) {
        __syncthreads();
        // --- B staging: copy pre-swizzled 32KB chunk (hi|lo) linearly ---
        short8 breg[8];
        const short8* bsrc = (const short8*)(w1bf + (size_t)c * 16384);
        #pragma unroll
        for (int i = 0; i < 8; ++i) breg[i] = bsrc[i * 256 + t];
        // --- A staging: load f32, split hi/lo bf16, swizzled ds_write ---
        #pragma unroll
        for (int i = 0; i < 4; ++i) {
            float4 v = *(const float4*)(features + fbase[i] + c * KCHUNK + akq[i] * 4);
            unsigned short hx = bf16_rne(v.x), hy = bf16_rne(v.y),
                           hz = bf16_rne(v.z), hw = bf16_rne(v.w);
            float lxf = v.x - __uint_as_float((unsigned int)hx << 16);
            float lyf = v.y - __uint_as_float((unsigned int)hy << 16);
            float lzf = v.z - __uint_as_float((unsigned int)hz << 16);
            float lwf = v.w - __uint_as_float((unsigned int)hw << 16);
            short4 hi4 = make_short4((short)hx, (short)hy, (short)hz, (short)hw);
            short4 lo4 = make_short4((short)bf16_rne(lxf), (short)bf16_rne(lyf),
                                     (short)bf16_rne(lzf), (short)bf16_rne(lwf));
            int off = arow[i] * 128 + ((akq[i] * 8) ^ ((arow[i] & 7) << 4));
            *(short4*)(s_raw + off)        = hi4;
            *(short4*)(s_raw + 8192 + off) = lo4;
        }
        {
            short8* bdst = (short8*)(s_raw + 16384);
            #pragma unroll
            for (int i = 0; i < 8; ++i) bdst[i * 256 + t] = breg[i];
        }
        __syncthreads();

        // --- compute: 2 k-steps of K=32, 3 MFMAs per (mf,nf) ---
        #pragma unroll
        for (int ks = 0; ks < 2; ++ks) {
            const int kb = ks * 64 + kq4 * 16;
            short8 bh[2], bl[2];
            #pragma unroll
            for (int nf = 0; nf < 2; ++nf) {
                int n = wv * 32 + nf * 16 + r15;
                int boff = n * 128 + (kb ^ ((n & 7) << 4));
                bh[nf] = *(const short8*)(s_raw + 16384 + boff);
                bl[nf] = *(const short8*)(s_raw + 32768 + boff);
            }
            #pragma unroll
            for (int mf = 0; mf < 4; ++mf) {
                int row  = mf * 16 + r15;
                int aoff = row * 128 + (kb ^ ((row & 7) << 4));
                short8 ah = *(const short8*)(s_raw + aoff);
                short8 al = *(const short8*)(s_raw + 8192 + aoff);
                #pragma unroll
                for (int nf = 0; nf < 2; ++nf) {
                    acc[mf][nf] = __builtin_amdgcn_mfma_f32_16x16x32_bf16(ah, bh[nf], acc[mf][nf], 0, 0, 0);
                    acc[mf][nf] = __builtin_amdgcn_mfma_f32_16x16x32_bf16(al, bh[nf], acc[mf][nf], 0, 0, 0);
                    acc[mf][nf] = __builtin_amdgcn_mfma_f32_16x16x32_bf16(ah, bl[nf], acc[mf][nf], 0, 0, 0);
                }
            }
        }
    }

    // --- epilogue: bias+relu, acc -> h tile in LDS (aliased, barrier-safe) ---
    __syncthreads();
    float* s_h = (float*)s_raw;
    #pragma unroll
    for (int nf = 0; nf < 2; ++nf) {
        int col = wv * 32 + nf * 16 + r15;
        float bias = b1[col];
        #pragma unroll
        for (int mf = 0; mf < 4; ++mf) {
            int row = mf * 16 + kq4 * 4;
            #pragma unroll
            for (int r = 0; r < 4; ++r)
                s_h[(row + r) * 132 + col] = fmaxf(acc[mf][nf][r] + bias, 0.f);
        }
    }
    __syncthreads();

    // --- GEMM2: 4 threads/row, 32 hid each ---
    const int lrow = t >> 2;   // 0..63
    const int part = t & 3;    // 0..3
    float l[6] = {0.f, 0.f, 0.f, 0.f, 0.f, 0.f};
    {
        const float* hp = s_h + lrow * 132 + part * 32;
        const float* wp = s_w2 + part * 32 * NE;
        #pragma unroll
        for (int g = 0; g < 8; ++g) {
            float4 h4 = *(const float4*)(hp + g * 4);
            float w[24];
            #pragma unroll
            for (int q = 0; q < 6; ++q)
                *(float4*)(w + q * 4) = *(const float4*)(wp + g * 24 + q * 4);
            #pragma unroll
            for (int e = 0; e < 6; ++e)
                l[e] += h4.x * w[e] + h4.y * w[6 + e] + h4.z * w[12 + e] + h4.w * w[18 + e];
        }
    }
    #pragma unroll
    for (int e = 0; e < 6; ++e) { l[e] += __shfl_xor(l[e], 1); l[e] += __shfl_xor(l[e], 2); }

    if (part == 0) {
        float lg[NE];
        #pragma unroll
        for (int e = 0; e < NE; ++e) lg[e] = l[e] + b2[e];
        float m = lg[0];
        #pragma unroll
        for (int e = 1; e < NE; ++e) m = fmaxf(m, lg[e]);
        float p[NE]; float psum = 0.f;
        #pragma unroll
        for (int e = 0; e < NE; ++e) { p[e] = expf(lg[e] - m); psum += p[e]; }
        #pragma unroll
        for (int e = 0; e < NE; ++e) p[e] = p[e] / psum;

        int i0 = 0; float v0 = p[0];
        #pragma unroll
        for (int e = 1; e < NE; ++e) if (p[e] > v0) { v0 = p[e]; i0 = e; }
        int i1 = -1; float v1 = -1e38f;
        #pragma unroll
        for (int e = 0; e < NE; ++e) if (e != i0 && p[e] > v1) { v1 = p[e]; i1 = e; }
        float v2 = -1e38f;
        #pragma unroll
        for (int e = 0; e < NE; ++e) if (e != i0 && e != i1 && p[e] > v2) v2 = p[e];

        int rowg = row0 + lrow;
        if (v1 - v2 < TAU) {  // selection not provably safe -> f32 recompute
            unsigned int slot = atomicAdd(count, 1u);
            if (slot < (unsigned int)M_TOTAL) rows[slot] = rowg;
        }

        float e1 = expf(v1 - v0);
        float rw0 = 1.f / (1.f + e1);
        float rw1 = e1 / (1.f + e1);

        int bb = rowg / NROW;
        int ss = rowg - bb * NROW;
        size_t bo0 = ((size_t)(i0 * NB + bb) * NQ + ss) * 4;
        size_t bo1 = ((size_t)(i1 * NB + bb) * NQ + ss) * 4;
        float4 g0 = *(const float4*)(ebox + bo0);
        float4 g1 = *(const float4*)(ebox + bo1);
        float4 ob;
        ob.x = rw0 * g0.x + rw1 * g1.x;
        ob.y = rw0 * g0.y + rw1 * g1.y;
        ob.z = rw0 * g0.z + rw1 * g1.z;
        ob.w = rw0 * g0.w + rw1 * g1.w;
        *(float4*)(out + (size_t)rowg * 4) = ob;

        size_t co0 = ((size_t)(i0 * NB + bb) * NQ + ss) * NC;
        size_t co1 = ((size_t)(i1 * NB + bb) * NQ + ss) * NC;
        float* oc = out + OUT_BBOX_SZ + (size_t)rowg * NC;
        #pragma unroll
        for (int k = 0; k < NC; ++k)
            oc[k] = rw0 * ecls[co0 + k] + rw1 * ecls[co1 + k];
    }
}

// ---- fix: worklist-driven f32 recompute, one block per flagged row ----
__global__ __launch_bounds__(256)
void moe_fix(const float* __restrict__ features, const float* __restrict__ W1,
             const float* __restrict__ b1, const float* __restrict__ W2,
             const float* __restrict__ b2, const float* __restrict__ ebox,
             const float* __restrict__ ecls, const unsigned int* __restrict__ count,
             const int* __restrict__ rows, float* __restrict__ out)
{
    __shared__ float s_f[DIN];
    __shared__ float s_part[HID];
    __shared__ float s_l[12];

    const int t = (int)threadIdx.x;
    const int n = (int)count[0];

    for (int it = (int)blockIdx.x; it < n; it += FIX_GRID) {
        int row = rows[it];
        int bb = row / NROW;
        int ss = row - bb * NROW;

        __syncthreads();  // protect s_f/s_part reuse across iterations
        s_f[t] = features[(size_t)(bb * SEQ + ss) * DIN + t];
        __syncthreads();

        const int col = t & 127;
        const int p   = t >> 7;   // d-half
        float a = 0.f;
        {
            const float* wp = W1 + p * (128 * HID) + col;
            const float* fp = s_f + p * 128;
            #pragma unroll 8
            for (int d = 0; d < 128; ++d) a = fmaf(fp[d], wp[(size_t)d * HID], a);
        }
        if (p == 1) s_part[col] = a;
        __syncthreads();

        if (t < 128) {
            float pre = a + s_part[t];
            float h = fmaxf(pre + b1[t], 0.f);
            float l[6];
            #pragma unroll
            for (int e = 0; e < 6; ++e) l[e] = h * W2[t * NE + e];
            #pragma unroll
            for (int off = 1; off < 64; off <<= 1) {
                #pragma unroll
                for (int e = 0; e < 6; ++e) l[e] += __shfl_xor(l[e], off);
            }
            if ((t & 63) == 0) {
                #pragma unroll
                for (int e = 0; e < 6; ++e) s_l[(t >> 6) * 6 + e] = l[e];
            }
        }
        __syncthreads();

        if (t == 0) {
            float lg[NE];
            #pragma unroll
            for (int e = 0; e < NE; ++e) lg[e] = s_l[e] + s_l[6 + e] + b2[e];
            float mx = lg[0];
            #pragma unroll
            for (int e = 1; e < NE; ++e) mx = fmaxf(mx, lg[e]);
            float pr[NE]; float psum = 0.f;
            #pragma unroll
            for (int e = 0; e < NE; ++e) { pr[e] = expf(lg[e] - mx); psum += pr[e]; }
            #pragma unroll
            for (int e = 0; e < NE; ++e) pr[e] = pr[e] / psum;

            int i0 = 0; float v0 = pr[0];
            #pragma unroll
            for (int e = 1; e < NE; ++e) if (pr[e] > v0) { v0 = pr[e]; i0 = e; }
            int i1 = -1; float v1 = -1e38f;
            #pragma unroll
            for (int e = 0; e < NE; ++e) if (e != i0 && pr[e] > v1) { v1 = pr[e]; i1 = e; }

            float e1 = expf(v1 - v0);
            float rw0 = 1.f / (1.f + e1);
            float rw1 = e1 / (1.f + e1);
            size_t bo0 = ((size_t)(i0 * NB + bb) * NQ + ss) * 4;
            size_t bo1 = ((size_t)(i1 * NB + bb) * NQ + ss) * 4;
            float4 g0 = *(const float4*)(ebox + bo0);
            float4 g1 = *(const float4*)(ebox + bo1);
            float4 ob;
            ob.x = rw0 * g0.x + rw1 * g1.x;
            ob.y = rw0 * g0.y + rw1 * g1.y;
            ob.z = rw0 * g0.z + rw1 * g1.z;
            ob.w = rw0 * g0.w + rw1 * g1.w;
            *(float4*)(out + (size_t)row * 4) = ob;
            size_t co0 = ((size_t)(i0 * NB + bb) * NQ + ss) * NC;
            size_t co1 = ((size_t)(i1 * NB + bb) * NQ + ss) * NC;
            float* oc = out + OUT_BBOX_SZ + (size_t)row * NC;
            #pragma unroll
            for (int k = 0; k < NC; ++k)
                oc[k] = rw0 * ecls[co0 + k] + rw1 * ecls[co1 + k];
        }
    }
}

extern "C" void kernel_launch(void* const* d_in, const int* in_sizes, int n_in,
                              void* d_out, int out_size, void* d_ws, size_t ws_size,
                              hipStream_t stream)
{
    const float* features = (const float*)d_in[0];
    const float* W1   = (const float*)d_in[1];
    const float* b1   = (const float*)d_in[2];
    const float* W2   = (const float*)d_in[3];
    const float* b2   = (const float*)d_in[4];
    const float* ebox = (const float*)d_in[5];
    const float* ecls = (const float*)d_in[6];
    float* out = (float*)d_out;

    unsigned int*   count = (unsigned int*)d_ws;
    int*            rows  = (int*)((char*)d_ws + WS_ROWS_OFF);
    unsigned short* w1bf  = (unsigned short*)((char*)d_ws + WS_W1BF_OFF);

    hipLaunchKernelGGL(moe_prep, dim3(129), dim3(256), 0, stream, W1, w1bf, count);
    hipLaunchKernelGGL(moe_main, dim3(NBLK), dim3(256), 0, stream,
                       features, b1, w1bf, W2, b2, ebox, ecls, count, rows, out);
    hipLaunchKernelGGL(moe_fix, dim3(FIX_GRID), dim3(256), 0, stream,
                       features, W1, b1, W2, b2, ebox, ecls, count, rows, out);
}